// Round 2
// 586.645 us; speedup vs baseline: 1.0238x; 1.0238x over previous
//
#include <hip/hip_runtime.h>
#include <math.h>

#define VOCAB 128000
#define EMB   32
#define HALF  16
#define BB    1024
#define SS    50

// native clang vector type for __builtin_nontemporal_store (HIP float4 is a
// class and is rejected by the builtin)
typedef float vfloat4 __attribute__((ext_vector_type(4)));

// ---------------------------------------------------------------------------
// Kernel 1 (fused): block-role split.
//   blocks [0, 500):   items role  -> ivT[k][v] = emb_weight[v].fc0_w[k] + fc0_b[k]
//   blocks [500, 756): hidden role -> per-row attention -> hiddenT[EMB][BB]
// ---------------------------------------------------------------------------
__global__ __launch_bounds__(256) void k_prep(
    const int*   __restrict__ text,
    const float* __restrict__ emb_weight,
    const float* __restrict__ fc0_w, const float* __restrict__ fc0_b,
    const float* __restrict__ att_wq, const float* __restrict__ att_wk,
    const float* __restrict__ att_v,
    const float* __restrict__ out_w, const float* __restrict__ out_b,
    float* __restrict__ ivT, float* __restrict__ hiddenT)
{
    __shared__ float s_fc0w[EMB * HALF];     // [e][h]
    __shared__ float s_fc0b[EMB];
    __shared__ float s_W[EMB * EMB];         // [j][e] = wq[j][e] + wk[j][e]
    __shared__ float s_av[EMB];
    __shared__ float s_owT[2 * EMB][EMB];    // [j][e2] = out_w[e2][j]
    __shared__ float s_ob[EMB];

    const int tid = threadIdx.x;
    const int bid = blockIdx.x;

    if (bid < VOCAB / 256) {
        // ---------------- items role ----------------
        for (int i = tid; i < EMB * HALF; i += 256) s_fc0w[i] = fc0_w[i];
        for (int i = tid; i < EMB; i += 256) s_fc0b[i] = fc0_b[i];
        __syncthreads();

        const int v = bid * 256 + tid;   // 500 blocks * 256 = 128000 exact
        const float4* erow = (const float4*)(emb_weight + (size_t)v * HALF);
        float4 q0 = erow[0], q1 = erow[1], q2 = erow[2], q3 = erow[3];
        float er[HALF] = {q0.x, q0.y, q0.z, q0.w, q1.x, q1.y, q1.z, q1.w,
                          q2.x, q2.y, q2.z, q2.w, q3.x, q3.y, q3.z, q3.w};
#pragma unroll
        for (int k = 0; k < EMB; k++) {
            float acc = s_fc0b[k];
#pragma unroll
            for (int h = 0; h < HALF; h++) acc += er[h] * s_fc0w[k * HALF + h];
            ivT[k * VOCAB + v] = acc;
        }
        return;
    }

    // ---------------- hidden role ----------------
    for (int i = tid; i < EMB * HALF; i += 256) s_fc0w[i] = fc0_w[i];
    for (int i = tid; i < EMB; i += 256) {
        s_fc0b[i] = fc0_b[i];
        s_av[i]   = att_v[i];
        s_ob[i]   = out_b[i];
    }
    for (int i = tid; i < EMB * EMB; i += 256) s_W[i] = att_wq[i] + att_wk[i];
    for (int i = tid; i < 2 * EMB * EMB; i += 256) {
        int e2 = i / (2 * EMB), j = i % (2 * EMB);
        s_owT[j][e2] = out_w[i];
    }
    __syncthreads();

    const int wave = tid >> 6;
    const int lane = tid & 63;
    const int b    = (bid - VOCAB / 256) * 4 + wave;

    const bool has   = (lane < SS);
    const int  t     = has ? text[b * SS + lane] : 0;   // row 0 is PAD (zeros) - safe
    const bool valid = has && (t != 0) && (t != 1);
    const float m    = valid ? 1.0f : 0.0f;

    // gather embedding row (16 floats)
    const float4* erow = (const float4*)(emb_weight + (size_t)t * HALF);
    float4 q0 = erow[0], q1 = erow[1], q2 = erow[2], q3 = erow[3];
    float er[HALF] = {q0.x, q0.y, q0.z, q0.w, q1.x, q1.y, q1.z, q1.w,
                      q2.x, q2.y, q2.z, q2.w, q3.x, q3.y, q3.z, q3.w};

    // embedded[s][e] = (er . fc0_w[e]) + fc0_b[e], masked
    float emb[EMB];
#pragma unroll
    for (int e = 0; e < EMB; e++) {
        float acc = s_fc0b[e];
#pragma unroll
        for (int h = 0; h < HALF; h++) acc += er[h] * s_fc0w[e * HALF + h];
        emb[e] = acc * m;
    }

    // score_s = sum_j tanh(emb . W[j]) * av[j]
    float sc = 0.0f;
#pragma unroll
    for (int j = 0; j < EMB; j++) {
        float acc = 0.0f;
#pragma unroll
        for (int e = 0; e < EMB; e++) acc += emb[e] * s_W[j * EMB + e];
        sc += tanhf(acc) * s_av[j];
    }
    sc = valid ? sc : -1e9f;
    if (!has) sc = -INFINITY;   // padding lanes contribute exp()=0

    // wave softmax over 64 lanes
    float mx = sc;
#pragma unroll
    for (int off = 32; off >= 1; off >>= 1) mx = fmaxf(mx, __shfl_xor(mx, off));
    float ex = expf(sc - mx);
    float sum = ex;
#pragma unroll
    for (int off = 32; off >= 1; off >>= 1) sum += __shfl_xor(sum, off);
    const float attn = ex / sum;

    // sl = embedded[:, 49, :]  (grab before emb is repurposed)
    float slv[EMB];
#pragma unroll
    for (int e = 0; e < EMB; e++) slv[e] = __shfl(emb[e], 49);

    // sg[e] = sum_s attn_s * emb[s][e]  (butterfly; result in every lane)
#pragma unroll
    for (int e = 0; e < EMB; e++) emb[e] *= attn;
#pragma unroll
    for (int off = 32; off >= 1; off >>= 1) {
#pragma unroll
        for (int e = 0; e < EMB; e++) emb[e] += __shfl_xor(emb[e], off);
    }

    // hidden[e2] = [sg;sl] . out_w[e2] + out_b[e2]; lanes 0..31 each one e2
    if (lane < EMB) {
        float h = s_ob[lane];
#pragma unroll
        for (int j = 0; j < EMB; j++) h += emb[j] * s_owT[j][lane];
#pragma unroll
        for (int j = 0; j < EMB; j++) h += slv[j] * s_owT[EMB + j][lane];
        hiddenT[lane * BB + b] = h;
    }
}

// ---------------------------------------------------------------------------
// Kernel 2: out[b][v] = hidden[b] . item_vecs[v]   (rank-32, the 524 MB write)
// 16 b-rows/thread (acc = 64 VGPR) -> 4 blocks/CU, finer compute/store
// interleave so the HBM write stream stays saturated. Nontemporal stores keep
// the 3.2 MB ivT chunk slice resident in each XCD L2.
// Chunk swizzle: 25 v-blocks x all 64 b-blocks per chunk.
// ---------------------------------------------------------------------------
__global__ __launch_bounds__(256, 4) void k_out(
    const float* __restrict__ ivT,
    const float* __restrict__ hiddenT,
    float* __restrict__ out)
{
    const int XB = 25, YB = 64;            // 125 v-blocks total, 64 b-blocks
    const int id    = blockIdx.x;          // 8000 blocks
    const int chunk = id / (XB * YB);
    const int r     = id % (XB * YB);
    const int xb    = chunk * XB + (r % XB);   // 0..124
    const int b0    = (r / XB) * 16;           // 0..1008

    const int vq = xb * 256 + threadIdx.x;     // v-quad index; v = 4*vq

    float4 acc[16];
#pragma unroll
    for (int j = 0; j < 16; j++) acc[j] = make_float4(0.f, 0.f, 0.f, 0.f);

    const float4* iv4 = (const float4*)ivT;    // [k][VOCAB/4]
#pragma unroll 8
    for (int k = 0; k < EMB; k++) {
        const float4 iv = iv4[k * (VOCAB / 4) + vq];
        const float* hr = hiddenT + k * BB + b0;   // uniform address -> s_load
#pragma unroll
        for (int j = 0; j < 16; j++) {
            const float h = hr[j];
            acc[j].x += iv.x * h;
            acc[j].y += iv.y * h;
            acc[j].z += iv.z * h;
            acc[j].w += iv.w * h;
        }
    }

    vfloat4* o4 = (vfloat4*)out;
#pragma unroll
    for (int j = 0; j < 16; j++) {
        vfloat4 s;
        s.x = acc[j].x; s.y = acc[j].y; s.z = acc[j].z; s.w = acc[j].w;
        __builtin_nontemporal_store(s, &o4[(b0 + j) * (VOCAB / 4) + vq]);
    }
}

// ---------------------------------------------------------------------------
extern "C" void kernel_launch(void* const* d_in, const int* in_sizes, int n_in,
                              void* d_out, int out_size, void* d_ws, size_t ws_size,
                              hipStream_t stream) {
    const int*   text       = (const int*)  d_in[0];
    const float* emb_weight = (const float*)d_in[1];
    const float* fc0_w      = (const float*)d_in[2];
    const float* fc0_b      = (const float*)d_in[3];
    const float* att_wq     = (const float*)d_in[4];
    const float* att_wk     = (const float*)d_in[5];
    const float* att_v      = (const float*)d_in[6];
    const float* out_w      = (const float*)d_in[7];
    const float* out_b      = (const float*)d_in[8];
    float* out = (float*)d_out;

    // workspace layout
    float* ivT     = (float*)d_ws;                               // 32*128000*4 = 16,384,000 B
    float* hiddenT = (float*)((char*)d_ws + (size_t)EMB * VOCAB * sizeof(float)); // 32*1024*4

    k_prep<<<VOCAB / 256 + BB / 4, 256, 0, stream>>>(
        text, emb_weight, fc0_w, fc0_b, att_wq, att_wk, att_v, out_w, out_b,
        ivT, hiddenT);
    k_out<<<8000, 256, 0, stream>>>(ivT, hiddenT, out);
}